// Round 2
// baseline (629.474 us; speedup 1.0000x reference)
//
#include <hip/hip_runtime.h>
#include <hip/hip_bf16.h>

#define N_NODES 50000
#define N_EDGES 800000
#define FT 128
#define HID 128

// ---------------- CSR build ----------------

__global__ __launch_bounds__(256) void hist_kernel(const int* __restrict__ dst,
                                                   int* __restrict__ cnt) {
    int e = blockIdx.x * 256 + threadIdx.x;
    if (e < N_EDGES) atomicAdd(&cnt[dst[e]], 1);
}

// wave-scan allocation of CSR offsets (grouping order arbitrary; sums don't care)
__global__ __launch_bounds__(256) void alloc_offsets_kernel(const int* __restrict__ cnt,
                                                            int* __restrict__ offs,
                                                            int* __restrict__ cursor,
                                                            int* __restrict__ gcur) {
    int i = blockIdx.x * 256 + threadIdx.x;
    int lane = threadIdx.x & 63;
    int c = (i < N_NODES) ? cnt[i] : 0;
    int pre = c;
    #pragma unroll
    for (int d = 1; d < 64; d <<= 1) {
        int t = __shfl_up(pre, d);
        if (lane >= d) pre += t;
    }
    int base = 0;
    if (lane == 63) base = atomicAdd(gcur, pre);  // pre at lane63 == wave total
    base = __shfl(base, 63);
    int o = base + pre - c;
    if (i < N_NODES) { offs[i] = o; cursor[i] = o; }
}

__global__ __launch_bounds__(256) void scatter_kernel(const int* __restrict__ src,
                                                      const int* __restrict__ dst,
                                                      int* __restrict__ cursor,
                                                      int* __restrict__ csr) {
    int e = blockIdx.x * 256 + threadIdx.x;
    if (e < N_EDGES) {
        int d = dst[e];
        int pos = atomicAdd(&cursor[d], 1);
        csr[pos] = src[e];
    }
}

// ---------------- aggregation: h = x + sum_{j->i} x_j ----------------
// one wave per node; lane holds 2 floats (float2), 64 lanes * 8B = 512B/row
__global__ __launch_bounds__(256) void agg_kernel(const float* __restrict__ x,
                                                  const int* __restrict__ csr,
                                                  const int* __restrict__ offs,
                                                  const int* __restrict__ cnt,
                                                  float* __restrict__ h) {
    int node = blockIdx.x * 4 + (threadIdx.x >> 6);
    int lane = threadIdx.x & 63;
    if (node >= N_NODES) return;
    const float2* x2 = (const float2*)x;
    int off = offs[node];
    int c = cnt[node];
    float2 acc = x2[(size_t)node * 64 + lane];  // the +x (eps=0) term
    int e = 0;
    for (; e + 4 <= c; e += 4) {
        int s0 = csr[off + e + 0];
        int s1 = csr[off + e + 1];
        int s2 = csr[off + e + 2];
        int s3 = csr[off + e + 3];
        float2 v0 = x2[(size_t)s0 * 64 + lane];
        float2 v1 = x2[(size_t)s1 * 64 + lane];
        float2 v2 = x2[(size_t)s2 * 64 + lane];
        float2 v3 = x2[(size_t)s3 * 64 + lane];
        acc.x += (v0.x + v1.x) + (v2.x + v3.x);
        acc.y += (v0.y + v1.y) + (v2.y + v3.y);
    }
    for (; e < c; ++e) {
        int s = csr[off + e];
        float2 v = x2[(size_t)s * 64 + lane];
        acc.x += v.x;
        acc.y += v.y;
    }
    ((float2*)h)[(size_t)node * 64 + lane] = acc;
}

// ---------------- fused MLP: out = relu(relu(h@W1+b1)@W2+b2) ----------------
// block = 256 threads, 64 nodes/block. Register tile: 4 nodes x 8 outs/thread.
// LDS: W k-chunk 16KB + h chunk 9.2KB + t (intermediate) 33.8KB = 59.4KB
__global__ __launch_bounds__(256) void mlp_kernel(const float* __restrict__ hin,
                                                  const float* __restrict__ W1,
                                                  const float* __restrict__ b1,
                                                  const float* __restrict__ W2,
                                                  const float* __restrict__ b2,
                                                  float* __restrict__ xout) {
    __shared__ float sW[32][128];   // k-chunk of weights [k][j]
    __shared__ float sH[64][36];    // node-chunk inputs, pad 36: f4-aligned, 2-way free
    __shared__ float sT[64][132];   // intermediate, pad 132: f4-aligned, 2-way free

    const int tid = threadIdx.x;
    const int og = tid & 15;   // output group: j0 = og*8
    const int ng = tid >> 4;   // node group: rows ng*4 .. +3
    const int nbase = blockIdx.x * 64;

    float acc[4][8];
    #pragma unroll
    for (int r = 0; r < 4; ++r)
        #pragma unroll
        for (int c = 0; c < 8; ++c) acc[r][c] = 0.f;

    // ---- stage 1: t = relu(h@W1 + b1) ----
    const float4* W14 = (const float4*)W1;
    for (int kc = 0; kc < 4; ++kc) {
        #pragma unroll
        for (int i = 0; i < 4; ++i) {
            int idx = tid + i * 256;  // 0..1023
            ((float4*)sW)[idx] = W14[kc * 1024 + idx];
        }
        #pragma unroll
        for (int i = 0; i < 2; ++i) {
            int idx = tid + i * 256;  // 0..511
            int n = idx >> 3, c4 = idx & 7;
            int gn = nbase + n;
            float4 v = make_float4(0.f, 0.f, 0.f, 0.f);
            if (gn < N_NODES) v = ((const float4*)hin)[(size_t)gn * 32 + kc * 8 + c4];
            *(float4*)&sH[n][c4 * 4] = v;
        }
        __syncthreads();
        #pragma unroll
        for (int k = 0; k < 32; ++k) {
            float a[4];
            #pragma unroll
            for (int r = 0; r < 4; ++r) a[r] = sH[ng * 4 + r][k];
            float w[8];
            *(float4*)&w[0] = *(const float4*)&sW[k][og * 8];
            *(float4*)&w[4] = *(const float4*)&sW[k][og * 8 + 4];
            #pragma unroll
            for (int r = 0; r < 4; ++r)
                #pragma unroll
                for (int c = 0; c < 8; ++c) acc[r][c] += a[r] * w[c];
        }
        __syncthreads();
    }
    #pragma unroll
    for (int r = 0; r < 4; ++r) {
        int n = ng * 4 + r;
        #pragma unroll
        for (int c = 0; c < 8; ++c) {
            float v = acc[r][c] + b1[og * 8 + c];
            sT[n][og * 8 + c] = v > 0.f ? v : 0.f;
            acc[r][c] = 0.f;
        }
    }
    __syncthreads();

    // ---- stage 2: out = relu(t@W2 + b2) ----
    const float4* W24 = (const float4*)W2;
    for (int kc = 0; kc < 4; ++kc) {
        #pragma unroll
        for (int i = 0; i < 4; ++i) {
            int idx = tid + i * 256;
            ((float4*)sW)[idx] = W24[kc * 1024 + idx];
        }
        __syncthreads();
        #pragma unroll
        for (int k = 0; k < 32; ++k) {
            int kk = kc * 32 + k;
            float a[4];
            #pragma unroll
            for (int r = 0; r < 4; ++r) a[r] = sT[ng * 4 + r][kk];
            float w[8];
            *(float4*)&w[0] = *(const float4*)&sW[k][og * 8];
            *(float4*)&w[4] = *(const float4*)&sW[k][og * 8 + 4];
            #pragma unroll
            for (int r = 0; r < 4; ++r)
                #pragma unroll
                for (int c = 0; c < 8; ++c) acc[r][c] += a[r] * w[c];
        }
        __syncthreads();
    }
    #pragma unroll
    for (int r = 0; r < 4; ++r) {
        int gn = nbase + ng * 4 + r;
        if (gn < N_NODES) {
            float o[8];
            #pragma unroll
            for (int c = 0; c < 8; ++c) {
                float v = acc[r][c] + b2[og * 8 + c];
                o[c] = v > 0.f ? v : 0.f;
            }
            ((float4*)xout)[(size_t)gn * 32 + og * 2 + 0] = *(float4*)&o[0];
            ((float4*)xout)[(size_t)gn * 32 + og * 2 + 1] = *(float4*)&o[4];
        }
    }
}

// ---------------- launch ----------------

extern "C" void kernel_launch(void* const* d_in, const int* in_sizes, int n_in,
                              void* d_out, int out_size, void* d_ws, size_t ws_size,
                              hipStream_t stream) {
    const float* feat = (const float*)d_in[0];
    const int* edge = (const int*)d_in[1];
    const int* src = edge;
    const int* dst = edge + N_EDGES;
    const float* W1a = (const float*)d_in[2];
    const float* b1a = (const float*)d_in[3];
    const float* W2a = (const float*)d_in[4];
    const float* b2a = (const float*)d_in[5];
    const float* Ws1 = (const float*)d_in[6];
    const float* bs1 = (const float*)d_in[7];
    const float* Ws2 = (const float*)d_in[8];
    const float* bs2 = (const float*)d_in[9];
    float* out = (float*)d_out;

    // workspace layout (ints): cnt | offs | cursor | gcur(pad 64) | csr | h | x
    int* cnt = (int*)d_ws;
    int* offs = cnt + 50176;
    int* cursor = offs + 50176;
    int* gcur = cursor + 50176;
    int* csr = gcur + 64;
    float* hbuf = (float*)(csr + N_EDGES);   // byte offset 3,802,368 (16B aligned)
    float* xbuf = hbuf + (size_t)N_NODES * HID;

    hipMemsetAsync(cnt, 0, N_NODES * sizeof(int), stream);
    hipMemsetAsync(gcur, 0, sizeof(int), stream);

    const int EB = (N_EDGES + 255) / 256;   // 3125
    const int NB = (N_NODES + 255) / 256;   // 196
    hist_kernel<<<EB, 256, 0, stream>>>(dst, cnt);
    alloc_offsets_kernel<<<NB, 256, 0, stream>>>(cnt, offs, cursor, gcur);
    scatter_kernel<<<EB, 256, 0, stream>>>(src, dst, cursor, csr);

    const int AGG_B = (N_NODES + 3) / 4;     // 12500 blocks, 4 nodes each
    const int MLP_B = (N_NODES + 63) / 64;   // 782 blocks

    // layer 0: feat -> xbuf
    agg_kernel<<<AGG_B, 256, 0, stream>>>(feat, csr, offs, cnt, hbuf);
    mlp_kernel<<<MLP_B, 256, 0, stream>>>(hbuf, W1a, b1a, W2a, b2a, xbuf);
    // layer 1: xbuf -> xbuf
    agg_kernel<<<AGG_B, 256, 0, stream>>>(xbuf, csr, offs, cnt, hbuf);
    mlp_kernel<<<MLP_B, 256, 0, stream>>>(hbuf, Ws1, bs1, Ws2, bs2, xbuf);
    // layer 2: xbuf -> out
    agg_kernel<<<AGG_B, 256, 0, stream>>>(xbuf, csr, offs, cnt, hbuf);
    mlp_kernel<<<MLP_B, 256, 0, stream>>>(hbuf, Ws1 + HID * HID, bs1 + HID,
                                          Ws2 + HID * HID, bs2 + HID, out);
}

// Round 4
// 442.145 us; speedup vs baseline: 1.4237x; 1.4237x over previous
//
#include <hip/hip_runtime.h>
#include <hip/hip_bf16.h>

#define N_NODES 50000
#define N_EDGES 800000
#define HID 128

typedef __attribute__((ext_vector_type(8))) short bf16x8;
typedef __attribute__((ext_vector_type(4))) float f32x4;
typedef __attribute__((ext_vector_type(4))) short short4v;

__device__ inline ushort f32_to_bf16_bits(float v) {
    union { float f; unsigned u; } a; a.f = v;
    unsigned r = a.u + 0x7fff + ((a.u >> 16) & 1);  // RNE
    return (ushort)(r >> 16);
}
__device__ inline float bf16bits_to_f32(ushort b) {
    union { float f; unsigned u; } a; a.u = ((unsigned)b) << 16;
    return a.f;
}

// ---------------- CSR build ----------------

__global__ __launch_bounds__(256) void hist_kernel(const int* __restrict__ dst,
                                                   int* __restrict__ cnt) {
    int e = blockIdx.x * 256 + threadIdx.x;
    if (e < N_EDGES) atomicAdd(&cnt[dst[e]], 1);
}

__global__ __launch_bounds__(256) void alloc_offsets_kernel(const int* __restrict__ cnt,
                                                            int* __restrict__ offs,
                                                            int* __restrict__ cursor,
                                                            int* __restrict__ gcur) {
    int i = blockIdx.x * 256 + threadIdx.x;
    int lane = threadIdx.x & 63;
    int c = (i < N_NODES) ? cnt[i] : 0;
    int pre = c;
    #pragma unroll
    for (int d = 1; d < 64; d <<= 1) {
        int t = __shfl_up(pre, d);
        if (lane >= d) pre += t;
    }
    int base = 0;
    if (lane == 63) base = atomicAdd(gcur, pre);
    base = __shfl(base, 63);
    int o = base + pre - c;
    if (i < N_NODES) { offs[i] = o; cursor[i] = o; }
}

__global__ __launch_bounds__(256) void scatter_kernel(const int* __restrict__ src,
                                                      const int* __restrict__ dst,
                                                      int* __restrict__ cursor,
                                                      int* __restrict__ csr) {
    int e = blockIdx.x * 256 + threadIdx.x;
    if (e < N_EDGES) {
        int d = dst[e];
        int pos = atomicAdd(&cursor[d], 1);
        csr[pos] = src[e];
    }
}

// ---------------- aggregation: h = x + sum_{j->i} x_j ----------------

__global__ __launch_bounds__(256) void agg_kernel(const float* __restrict__ x,
                                                  const int* __restrict__ csr,
                                                  const int* __restrict__ offs,
                                                  const int* __restrict__ cnt,
                                                  float* __restrict__ h) {
    int node = blockIdx.x * 4 + (threadIdx.x >> 6);
    int lane = threadIdx.x & 63;
    if (node >= N_NODES) return;
    const float2* x2 = (const float2*)x;
    int off = offs[node];
    int c = cnt[node];
    float2 acc = x2[(size_t)node * 64 + lane];
    int e = 0;
    for (; e + 4 <= c; e += 4) {
        int s0 = csr[off + e + 0];
        int s1 = csr[off + e + 1];
        int s2 = csr[off + e + 2];
        int s3 = csr[off + e + 3];
        float2 v0 = x2[(size_t)s0 * 64 + lane];
        float2 v1 = x2[(size_t)s1 * 64 + lane];
        float2 v2 = x2[(size_t)s2 * 64 + lane];
        float2 v3 = x2[(size_t)s3 * 64 + lane];
        acc.x += (v0.x + v1.x) + (v2.x + v3.x);
        acc.y += (v0.y + v1.y) + (v2.y + v3.y);
    }
    for (; e < c; ++e) {
        int s = csr[off + e];
        float2 v = x2[(size_t)s * 64 + lane];
        acc.x += v.x;
        acc.y += v.y;
    }
    ((float2*)h)[(size_t)node * 64 + lane] = acc;
}

// ---------------- weight prep: fragment-linear hi/lo bf16 ----------------
// Frag layout rule (shared by A and B packing -> k-permutation cancels):
//   elem i of lane l in k-chunk t covers k = t*32 + (l>>4)*8 + i, col/row = f*16 + (l&15)
// out[ mat ][ ((f*4 + t)*64 + l)*8 + i ]

__global__ __launch_bounds__(256) void prep_kernel(const float* __restrict__ W1a,
                                                   const float* __restrict__ W2a,
                                                   const float* __restrict__ Ws1,
                                                   const float* __restrict__ Ws2,
                                                   short* __restrict__ whi,
                                                   short* __restrict__ wlo) {
    int mat = blockIdx.y;  // 0..5
    const float* W;
    switch (mat) {
        case 0: W = W1a; break;
        case 1: W = W2a; break;
        case 2: W = Ws1; break;
        case 3: W = Ws2; break;
        case 4: W = Ws1 + HID * HID; break;
        default: W = Ws2 + HID * HID; break;
    }
    int tid2 = blockIdx.x * 256 + threadIdx.x;  // 0..2047
    int l = tid2 & 63;
    int ft = tid2 >> 6;       // f*4 + t
    int t = ft & 3, f = ft >> 2;
    int g = l >> 4, lm = l & 15;
    bf16x8 hv, lv;
    #pragma unroll
    for (int i = 0; i < 8; ++i) {
        int k = t * 32 + g * 8 + i;
        int n = f * 16 + lm;
        float v = W[k * HID + n];
        ushort hb = f32_to_bf16_bits(v);
        ushort lb = f32_to_bf16_bits(v - bf16bits_to_f32(hb));
        hv[i] = (short)hb;
        lv[i] = (short)lb;
    }
    size_t base = ((size_t)mat * 2048 + tid2) * 8;
    *(bf16x8*)&whi[base] = hv;
    *(bf16x8*)&wlo[base] = lv;
}

// ---------------- fused MLP via split-bf16 MFMA ----------------
// block = 256 thr = 4 waves, 64 nodes/block. Wave w owns rows w*16..w*16+15.
// LDS stride 136 shorts (272 B): 16B-aligned b128 frag reads, <=2-way banks (free).

__global__ __launch_bounds__(256) void mlp_kernel(const float* __restrict__ hin,
                                                  const short* __restrict__ w1hi,
                                                  const short* __restrict__ w1lo,
                                                  const short* __restrict__ w2hi,
                                                  const short* __restrict__ w2lo,
                                                  const float* __restrict__ b1,
                                                  const float* __restrict__ b2,
                                                  float* __restrict__ xout) {
    __shared__ short sHi[64][136];
    __shared__ short sLo[64][136];

    const int tid = threadIdx.x;
    const int nbase = blockIdx.x * 64;
    const int lane = tid & 63;
    const int wid = tid >> 6;
    const int g = lane >> 4, lm = lane & 15;
    const int wrow = wid * 16;

    // ---- stage h -> hi/lo bf16 LDS ----
    #pragma unroll
    for (int i = 0; i < 8; ++i) {
        int j = tid + i * 256;        // float4 slot 0..2047
        int row = j >> 5, c4 = j & 31;
        int gn = nbase + row;
        float4 v = make_float4(0.f, 0.f, 0.f, 0.f);
        if (gn < N_NODES) v = ((const float4*)hin)[(size_t)gn * 32 + c4];
        short4v hs, ls;
        float vv[4] = {v.x, v.y, v.z, v.w};
        #pragma unroll
        for (int q = 0; q < 4; ++q) {
            ushort hb = f32_to_bf16_bits(vv[q]);
            ushort lb = f32_to_bf16_bits(vv[q] - bf16bits_to_f32(hb));
            hs[q] = (short)hb;
            ls[q] = (short)lb;
        }
        *(short4v*)&sHi[row][c4 * 4] = hs;
        *(short4v*)&sLo[row][c4 * 4] = ls;
    }
    __syncthreads();

    f32x4 accT[8];

    // ---- GEMM1: T = relu(h @ W1 + b1) ----
    {
        bf16x8 ahi[4], alo[4];
        #pragma unroll
        for (int t = 0; t < 4; ++t) {
            ahi[t] = *(bf16x8*)&sHi[wrow + lm][t * 32 + g * 8];
            alo[t] = *(bf16x8*)&sLo[wrow + lm][t * 32 + g * 8];
        }
        #pragma unroll
        for (int f = 0; f < 8; ++f) {
            const bf16x8* bh = (const bf16x8*)&w1hi[((size_t)(f * 4) * 64 + lane) * 8];
            const bf16x8* bl = (const bf16x8*)&w1lo[((size_t)(f * 4) * 64 + lane) * 8];
            f32x4 acc = {0.f, 0.f, 0.f, 0.f};
            #pragma unroll
            for (int t = 0; t < 4; ++t) {
                bf16x8 bhv = bh[t * 64];
                bf16x8 blv = bl[t * 64];
                acc = __builtin_amdgcn_mfma_f32_16x16x32_bf16(ahi[t], bhv, acc, 0, 0, 0);
                acc = __builtin_amdgcn_mfma_f32_16x16x32_bf16(alo[t], bhv, acc, 0, 0, 0);
                acc = __builtin_amdgcn_mfma_f32_16x16x32_bf16(ahi[t], blv, acc, 0, 0, 0);
            }
            accT[f] = acc;
        }
    }
    // epilogue 1: bias+relu, split hi/lo, write own-wave rows back to LDS
    // (wave-private rows: no barrier needed; same-wave RAW handled by lgkmcnt)
    #pragma unroll
    for (int f = 0; f < 8; ++f) {
        float bv = b1[f * 16 + lm];
        #pragma unroll
        for (int r = 0; r < 4; ++r) {
            float v = accT[f][r] + bv;
            v = v > 0.f ? v : 0.f;
            ushort hb = f32_to_bf16_bits(v);
            ushort lb = f32_to_bf16_bits(v - bf16bits_to_f32(hb));
            int m = wrow + g * 4 + r;          // C/D: row=(lane>>4)*4+reg, col=lane&15
            sHi[m][f * 16 + lm] = (short)hb;
            sLo[m][f * 16 + lm] = (short)lb;
        }
    }

    // ---- GEMM2: out = relu(T @ W2 + b2) ----
    {
        bf16x8 ahi[4], alo[4];
        #pragma unroll
        for (int t = 0; t < 4; ++t) {
            ahi[t] = *(bf16x8*)&sHi[wrow + lm][t * 32 + g * 8];
            alo[t] = *(bf16x8*)&sLo[wrow + lm][t * 32 + g * 8];
        }
        #pragma unroll
        for (int f = 0; f < 8; ++f) {
            const bf16x8* bh = (const bf16x8*)&w2hi[((size_t)(f * 4) * 64 + lane) * 8];
            const bf16x8* bl = (const bf16x8*)&w2lo[((size_t)(f * 4) * 64 + lane) * 8];
            f32x4 acc = {0.f, 0.f, 0.f, 0.f};
            #pragma unroll
            for (int t = 0; t < 4; ++t) {
                bf16x8 bhv = bh[t * 64];
                bf16x8 blv = bl[t * 64];
                acc = __builtin_amdgcn_mfma_f32_16x16x32_bf16(ahi[t], bhv, acc, 0, 0, 0);
                acc = __builtin_amdgcn_mfma_f32_16x16x32_bf16(alo[t], bhv, acc, 0, 0, 0);
                acc = __builtin_amdgcn_mfma_f32_16x16x32_bf16(ahi[t], blv, acc, 0, 0, 0);
            }
            accT[f] = acc;
        }
    }
    // epilogue 2: bias+relu, f32 store
    #pragma unroll
    for (int f = 0; f < 8; ++f) {
        float bv = b2[f * 16 + lm];
        #pragma unroll
        for (int r = 0; r < 4; ++r) {
            float v = accT[f][r] + bv;
            v = v > 0.f ? v : 0.f;
            int gn = nbase + wrow + g * 4 + r;
            if (gn < N_NODES) xout[(size_t)gn * HID + f * 16 + lm] = v;
        }
    }
}

// ---------------- launch ----------------

extern "C" void kernel_launch(void* const* d_in, const int* in_sizes, int n_in,
                              void* d_out, int out_size, void* d_ws, size_t ws_size,
                              hipStream_t stream) {
    const float* feat = (const float*)d_in[0];
    const int* edge = (const int*)d_in[1];
    const int* src = edge;
    const int* dst = edge + N_EDGES;
    const float* W1a = (const float*)d_in[2];
    const float* b1a = (const float*)d_in[3];
    const float* W2a = (const float*)d_in[4];
    const float* b2a = (const float*)d_in[5];
    const float* Ws1 = (const float*)d_in[6];
    const float* bs1 = (const float*)d_in[7];
    const float* Ws2 = (const float*)d_in[8];
    const float* bs2 = (const float*)d_in[9];
    float* out = (float*)d_out;

    // ws layout: cnt | offs | cursor | gcur(pad) | csr | hbuf | xbuf | whi | wlo
    int* cnt = (int*)d_ws;
    int* offs = cnt + 50176;
    int* cursor = offs + 50176;
    int* gcur = cursor + 50176;
    int* csr = gcur + 64;
    float* hbuf = (float*)(csr + N_EDGES);
    float* xbuf = hbuf + (size_t)N_NODES * HID;
    short* whi = (short*)(xbuf + (size_t)N_NODES * HID);
    short* wlo = whi + 6 * 2048 * 8;

    hipMemsetAsync(cnt, 0, N_NODES * sizeof(int), stream);
    hipMemsetAsync(gcur, 0, sizeof(int), stream);

    const int EB = (N_EDGES + 255) / 256;
    const int NB = (N_NODES + 255) / 256;
    prep_kernel<<<dim3(8, 6), 256, 0, stream>>>(W1a, W2a, Ws1, Ws2, whi, wlo);
    hist_kernel<<<EB, 256, 0, stream>>>(dst, cnt);
    alloc_offsets_kernel<<<NB, 256, 0, stream>>>(cnt, offs, cursor, gcur);
    scatter_kernel<<<EB, 256, 0, stream>>>(src, dst, cursor, csr);

    const int AGG_B = (N_NODES + 3) / 4;
    const int MLP_B = (N_NODES + 63) / 64;   // 782

    // per-layer fragment-matrix pointers (mat order: W1a,W2a,Ws1[0],Ws2[0],Ws1[1],Ws2[1])
    const int MS = 16384;
    agg_kernel<<<AGG_B, 256, 0, stream>>>(feat, csr, offs, cnt, hbuf);
    mlp_kernel<<<MLP_B, 256, 0, stream>>>(hbuf, whi + 0 * MS, wlo + 0 * MS,
                                          whi + 1 * MS, wlo + 1 * MS, b1a, b2a, xbuf);
    agg_kernel<<<AGG_B, 256, 0, stream>>>(xbuf, csr, offs, cnt, hbuf);
    mlp_kernel<<<MLP_B, 256, 0, stream>>>(hbuf, whi + 2 * MS, wlo + 2 * MS,
                                          whi + 3 * MS, wlo + 3 * MS, bs1, bs2, xbuf);
    agg_kernel<<<AGG_B, 256, 0, stream>>>(xbuf, csr, offs, cnt, hbuf);
    mlp_kernel<<<MLP_B, 256, 0, stream>>>(hbuf, whi + 4 * MS, wlo + 4 * MS,
                                          whi + 5 * MS, wlo + 5 * MS,
                                          bs1 + HID, bs2 + HID, out);
}

// Round 5
// 385.373 us; speedup vs baseline: 1.6334x; 1.1473x over previous
//
#include <hip/hip_runtime.h>
#include <hip/hip_bf16.h>

#define N_NODES 50000
#define N_EDGES 800000
#define HID 128

typedef __attribute__((ext_vector_type(8))) short bf16x8;
typedef __attribute__((ext_vector_type(4))) float f32x4;

__device__ inline ushort f32_to_bf16_bits(float v) {
    union { float f; unsigned u; } a; a.f = v;
    unsigned r = a.u + 0x7fff + ((a.u >> 16) & 1);  // RNE
    return (ushort)(r >> 16);
}
__device__ inline float bf16bits_to_f32(ushort b) {
    union { float f; unsigned u; } a; a.u = ((unsigned)b) << 16;
    return a.f;
}

// ---------------- CSR build ----------------

__global__ __launch_bounds__(256) void hist_kernel(const int* __restrict__ dst,
                                                   int* __restrict__ cnt) {
    int e = blockIdx.x * 256 + threadIdx.x;
    if (e < N_EDGES) atomicAdd(&cnt[dst[e]], 1);
}

__global__ __launch_bounds__(256) void alloc_offsets_kernel(const int* __restrict__ cnt,
                                                            int* __restrict__ offs,
                                                            int* __restrict__ cursor,
                                                            int* __restrict__ gcur) {
    int i = blockIdx.x * 256 + threadIdx.x;
    int lane = threadIdx.x & 63;
    int c = (i < N_NODES) ? cnt[i] : 0;
    int pre = c;
    #pragma unroll
    for (int d = 1; d < 64; d <<= 1) {
        int t = __shfl_up(pre, d);
        if (lane >= d) pre += t;
    }
    int base = 0;
    if (lane == 63) base = atomicAdd(gcur, pre);
    base = __shfl(base, 63);
    int o = base + pre - c;
    if (i < N_NODES) { offs[i] = o; cursor[i] = o; }
}

__global__ __launch_bounds__(256) void scatter_kernel(const int* __restrict__ src,
                                                      const int* __restrict__ dst,
                                                      int* __restrict__ cursor,
                                                      int* __restrict__ csr) {
    int e = blockIdx.x * 256 + threadIdx.x;
    if (e < N_EDGES) {
        int d = dst[e];
        int pos = atomicAdd(&cursor[d], 1);
        csr[pos] = src[e];
    }
}

// ---------------- weight prep: fragment-linear hi/lo bf16 ----------------
// Shared (lane,elem)->k rule for A and B packing => any k-permutation cancels:
//   elem i of lane l in k-chunk t covers k = t*32 + (l>>4)*8 + i, col = f*16 + (l&15)

__global__ __launch_bounds__(256) void prep_kernel(const float* __restrict__ W1a,
                                                   const float* __restrict__ W2a,
                                                   const float* __restrict__ Ws1,
                                                   const float* __restrict__ Ws2,
                                                   short* __restrict__ whi,
                                                   short* __restrict__ wlo) {
    int mat = blockIdx.y;  // 0..5
    const float* W;
    switch (mat) {
        case 0: W = W1a; break;
        case 1: W = W2a; break;
        case 2: W = Ws1; break;
        case 3: W = Ws2; break;
        case 4: W = Ws1 + HID * HID; break;
        default: W = Ws2 + HID * HID; break;
    }
    int tid2 = blockIdx.x * 256 + threadIdx.x;  // 0..2047
    int l = tid2 & 63;
    int ft = tid2 >> 6;       // f*4 + t
    int t = ft & 3, f = ft >> 2;
    int g = l >> 4, lm = l & 15;
    bf16x8 hv, lv;
    #pragma unroll
    for (int i = 0; i < 8; ++i) {
        int k = t * 32 + g * 8 + i;
        int n = f * 16 + lm;
        float v = W[k * HID + n];
        ushort hb = f32_to_bf16_bits(v);
        ushort lb = f32_to_bf16_bits(v - bf16bits_to_f32(hb));
        hv[i] = (short)hb;
        lv[i] = (short)lb;
    }
    size_t base = ((size_t)mat * 2048 + tid2) * 8;
    *(bf16x8*)&whi[base] = hv;
    *(bf16x8*)&wlo[base] = lv;
}

// ---------------- fused GIN layer: out = relu(mlp(x + sum_{j->i} x_j)) ----------------
// One wave per block, 16 nodes per wave. Wave-private LDS rows -> NO barriers.
// LDS stride 136 shorts (272 B): 16B-aligned b128 frag reads, conflict-free.

__global__ __launch_bounds__(64) void fused_gin_kernel(const float* __restrict__ x,
                                                       const int* __restrict__ csr,
                                                       const int* __restrict__ offs,
                                                       const int* __restrict__ cnt,
                                                       const short* __restrict__ w1hi,
                                                       const short* __restrict__ w1lo,
                                                       const short* __restrict__ w2hi,
                                                       const short* __restrict__ w2lo,
                                                       const float* __restrict__ b1,
                                                       const float* __restrict__ b2,
                                                       float* __restrict__ xout) {
    __shared__ short sHi[16][136];
    __shared__ short sLo[16][136];

    const int lane = threadIdx.x;          // 0..63
    const int nbase = blockIdx.x * 16;     // 3125 * 16 == 50000 exactly
    const int g = lane >> 4, lm = lane & 15;
    const float2* x2 = (const float2*)x;

    // ---- gather phase: h[n] = x[n] + sum_j x[csr[j]], lane holds cols {2l,2l+1} ----
    for (int n = 0; n < 16; ++n) {
        int node = nbase + n;
        int off = offs[node];
        int c = cnt[node];
        float2 acc = x2[(size_t)node * 64 + lane];
        int e = 0;
        for (; e + 8 <= c; e += 8) {
            int s[8];
            #pragma unroll
            for (int q = 0; q < 8; ++q) s[q] = csr[off + e + q];
            float2 v[8];
            #pragma unroll
            for (int q = 0; q < 8; ++q) v[q] = x2[(size_t)s[q] * 64 + lane];
            acc.x += ((v[0].x + v[1].x) + (v[2].x + v[3].x)) +
                     ((v[4].x + v[5].x) + (v[6].x + v[7].x));
            acc.y += ((v[0].y + v[1].y) + (v[2].y + v[3].y)) +
                     ((v[4].y + v[5].y) + (v[6].y + v[7].y));
        }
        for (; e + 4 <= c; e += 4) {
            int s0 = csr[off + e], s1 = csr[off + e + 1];
            int s2 = csr[off + e + 2], s3 = csr[off + e + 3];
            float2 v0 = x2[(size_t)s0 * 64 + lane];
            float2 v1 = x2[(size_t)s1 * 64 + lane];
            float2 v2 = x2[(size_t)s2 * 64 + lane];
            float2 v3 = x2[(size_t)s3 * 64 + lane];
            acc.x += (v0.x + v1.x) + (v2.x + v3.x);
            acc.y += (v0.y + v1.y) + (v2.y + v3.y);
        }
        for (; e < c; ++e) {
            int s = csr[off + e];
            float2 v = x2[(size_t)s * 64 + lane];
            acc.x += v.x;
            acc.y += v.y;
        }
        // split hi/lo, pack two cols into one dword LDS write
        ushort hx = f32_to_bf16_bits(acc.x);
        ushort lx = f32_to_bf16_bits(acc.x - bf16bits_to_f32(hx));
        ushort hy = f32_to_bf16_bits(acc.y);
        ushort ly = f32_to_bf16_bits(acc.y - bf16bits_to_f32(hy));
        *(unsigned*)&sHi[n][2 * lane] = (unsigned)hx | ((unsigned)hy << 16);
        *(unsigned*)&sLo[n][2 * lane] = (unsigned)lx | ((unsigned)ly << 16);
    }
    // same-wave LDS RAW: compiler-inserted lgkmcnt, no barrier needed

    f32x4 accT[8];

    // ---- GEMM1: T = relu(h @ W1 + b1) ----
    {
        bf16x8 ahi[4], alo[4];
        #pragma unroll
        for (int t = 0; t < 4; ++t) {
            ahi[t] = *(bf16x8*)&sHi[lm][t * 32 + g * 8];
            alo[t] = *(bf16x8*)&sLo[lm][t * 32 + g * 8];
        }
        #pragma unroll
        for (int f = 0; f < 8; ++f) {
            const bf16x8* bh = (const bf16x8*)&w1hi[((size_t)(f * 4) * 64 + lane) * 8];
            const bf16x8* bl = (const bf16x8*)&w1lo[((size_t)(f * 4) * 64 + lane) * 8];
            f32x4 acc = {0.f, 0.f, 0.f, 0.f};
            #pragma unroll
            for (int t = 0; t < 4; ++t) {
                bf16x8 bhv = bh[t * 64];
                bf16x8 blv = bl[t * 64];
                acc = __builtin_amdgcn_mfma_f32_16x16x32_bf16(ahi[t], bhv, acc, 0, 0, 0);
                acc = __builtin_amdgcn_mfma_f32_16x16x32_bf16(alo[t], bhv, acc, 0, 0, 0);
                acc = __builtin_amdgcn_mfma_f32_16x16x32_bf16(ahi[t], blv, acc, 0, 0, 0);
            }
            accT[f] = acc;
        }
    }
    // epilogue 1: bias+relu, split hi/lo, write back (C/D: row=g*4+r, col=f*16+lm)
    #pragma unroll
    for (int f = 0; f < 8; ++f) {
        float bv = b1[f * 16 + lm];
        #pragma unroll
        for (int r = 0; r < 4; ++r) {
            float v = accT[f][r] + bv;
            v = v > 0.f ? v : 0.f;
            ushort hb = f32_to_bf16_bits(v);
            ushort lb = f32_to_bf16_bits(v - bf16bits_to_f32(hb));
            int m = g * 4 + r;
            sHi[m][f * 16 + lm] = (short)hb;
            sLo[m][f * 16 + lm] = (short)lb;
        }
    }

    // ---- GEMM2: out = relu(T @ W2 + b2) ----
    {
        bf16x8 ahi[4], alo[4];
        #pragma unroll
        for (int t = 0; t < 4; ++t) {
            ahi[t] = *(bf16x8*)&sHi[lm][t * 32 + g * 8];
            alo[t] = *(bf16x8*)&sLo[lm][t * 32 + g * 8];
        }
        #pragma unroll
        for (int f = 0; f < 8; ++f) {
            const bf16x8* bh = (const bf16x8*)&w2hi[((size_t)(f * 4) * 64 + lane) * 8];
            const bf16x8* bl = (const bf16x8*)&w2lo[((size_t)(f * 4) * 64 + lane) * 8];
            f32x4 acc = {0.f, 0.f, 0.f, 0.f};
            #pragma unroll
            for (int t = 0; t < 4; ++t) {
                bf16x8 bhv = bh[t * 64];
                bf16x8 blv = bl[t * 64];
                acc = __builtin_amdgcn_mfma_f32_16x16x32_bf16(ahi[t], bhv, acc, 0, 0, 0);
                acc = __builtin_amdgcn_mfma_f32_16x16x32_bf16(alo[t], bhv, acc, 0, 0, 0);
                acc = __builtin_amdgcn_mfma_f32_16x16x32_bf16(ahi[t], blv, acc, 0, 0, 0);
            }
            accT[f] = acc;
        }
    }
    // epilogue 2: bias+relu, f32 store
    #pragma unroll
    for (int f = 0; f < 8; ++f) {
        float bv = b2[f * 16 + lm];
        #pragma unroll
        for (int r = 0; r < 4; ++r) {
            float v = accT[f][r] + bv;
            v = v > 0.f ? v : 0.f;
            int gn = nbase + g * 4 + r;
            xout[(size_t)gn * HID + f * 16 + lm] = v;
        }
    }
}

// ---------------- launch ----------------

extern "C" void kernel_launch(void* const* d_in, const int* in_sizes, int n_in,
                              void* d_out, int out_size, void* d_ws, size_t ws_size,
                              hipStream_t stream) {
    const float* feat = (const float*)d_in[0];
    const int* edge = (const int*)d_in[1];
    const int* src = edge;
    const int* dst = edge + N_EDGES;
    const float* W1a = (const float*)d_in[2];
    const float* b1a = (const float*)d_in[3];
    const float* W2a = (const float*)d_in[4];
    const float* b2a = (const float*)d_in[5];
    const float* Ws1 = (const float*)d_in[6];
    const float* bs1 = (const float*)d_in[7];
    const float* Ws2 = (const float*)d_in[8];
    const float* bs2 = (const float*)d_in[9];
    float* out = (float*)d_out;

    // ws layout: cnt | offs | cursor | gcur(pad) | csr | xb0 | xb1 | whi | wlo
    int* cnt = (int*)d_ws;
    int* offs = cnt + 50176;
    int* cursor = offs + 50176;
    int* gcur = cursor + 50176;
    int* csr = gcur + 64;
    float* xb0 = (float*)(csr + N_EDGES);
    float* xb1 = xb0 + (size_t)N_NODES * HID;
    short* whi = (short*)(xb1 + (size_t)N_NODES * HID);
    short* wlo = whi + 6 * 2048 * 8;

    hipMemsetAsync(cnt, 0, N_NODES * sizeof(int), stream);
    hipMemsetAsync(gcur, 0, sizeof(int), stream);

    const int EB = (N_EDGES + 255) / 256;
    const int NB = (N_NODES + 255) / 256;
    prep_kernel<<<dim3(8, 6), 256, 0, stream>>>(W1a, W2a, Ws1, Ws2, whi, wlo);
    hist_kernel<<<EB, 256, 0, stream>>>(dst, cnt);
    alloc_offsets_kernel<<<NB, 256, 0, stream>>>(cnt, offs, cursor, gcur);
    scatter_kernel<<<EB, 256, 0, stream>>>(src, dst, cursor, csr);

    const int FB = N_NODES / 16;   // 3125 blocks, 16 nodes each, exact
    const int MS = 16384;          // per-matrix fragment array size (shorts)

    // mat order: W1a, W2a, Ws1[0], Ws2[0], Ws1[1], Ws2[1]; ping-pong x buffers
    fused_gin_kernel<<<FB, 64, 0, stream>>>(feat, csr, offs, cnt,
                                            whi + 0 * MS, wlo + 0 * MS,
                                            whi + 1 * MS, wlo + 1 * MS, b1a, b2a, xb0);
    fused_gin_kernel<<<FB, 64, 0, stream>>>(xb0, csr, offs, cnt,
                                            whi + 2 * MS, wlo + 2 * MS,
                                            whi + 3 * MS, wlo + 3 * MS, bs1, bs2, xb1);
    fused_gin_kernel<<<FB, 64, 0, stream>>>(xb1, csr, offs, cnt,
                                            whi + 4 * MS, wlo + 4 * MS,
                                            whi + 5 * MS, wlo + 5 * MS,
                                            bs1 + HID, bs2 + HID, out);
}

// Round 7
// 331.922 us; speedup vs baseline: 1.8964x; 1.1610x over previous
//
#include <hip/hip_runtime.h>
#include <hip/hip_bf16.h>

#define N_NODES 50000
#define N_EDGES 800000
#define HID 128

typedef __attribute__((ext_vector_type(8))) short bf16x8;
typedef __attribute__((ext_vector_type(4))) float f32x4;

__device__ inline ushort f32_to_bf16_bits(float v) {
    union { float f; unsigned u; } a; a.f = v;
    unsigned r = a.u + 0x7fff + ((a.u >> 16) & 1);  // RNE
    return (ushort)(r >> 16);
}
__device__ inline float bf16bits_to_f32(ushort b) {
    union { float f; unsigned u; } a; a.u = ((unsigned)b) << 16;
    return a.f;
}

// ---------------- CSR build ----------------

__global__ __launch_bounds__(256) void hist_kernel(const int* __restrict__ dst,
                                                   int* __restrict__ cnt) {
    int e = blockIdx.x * 256 + threadIdx.x;
    if (e < N_EDGES) atomicAdd(&cnt[dst[e]], 1);
}

__global__ __launch_bounds__(256) void alloc_offsets_kernel(const int* __restrict__ cnt,
                                                            int* __restrict__ offs,
                                                            int* __restrict__ cursor,
                                                            int* __restrict__ gcur) {
    int i = blockIdx.x * 256 + threadIdx.x;
    int lane = threadIdx.x & 63;
    int c = (i < N_NODES) ? cnt[i] : 0;
    int pre = c;
    #pragma unroll
    for (int d = 1; d < 64; d <<= 1) {
        int t = __shfl_up(pre, d);
        if (lane >= d) pre += t;
    }
    int base = 0;
    if (lane == 63) base = atomicAdd(gcur, pre);
    base = __shfl(base, 63);
    int o = base + pre - c;
    if (i < N_NODES) { offs[i] = o; cursor[i] = o; }
}

__global__ __launch_bounds__(256) void scatter_kernel(const int* __restrict__ src,
                                                      const int* __restrict__ dst,
                                                      int* __restrict__ cursor,
                                                      int* __restrict__ csr) {
    int e = blockIdx.x * 256 + threadIdx.x;
    if (e < N_EDGES) {
        int d = dst[e];
        int pos = atomicAdd(&cursor[d], 1);
        csr[pos] = src[e];
    }
}

// ---------------- feat (f32) -> bf16 table ----------------

__global__ __launch_bounds__(256) void conv_kernel(const float* __restrict__ in,
                                                   ushort* __restrict__ out) {
    int t = blockIdx.x * 256 + threadIdx.x;   // 800000 groups of 8 floats
    if (t >= (N_NODES * HID) / 8) return;
    const float4* in4 = (const float4*)in;
    float4 a = in4[2 * t], b = in4[2 * t + 1];
    float v[8] = {a.x, a.y, a.z, a.w, b.x, b.y, b.z, b.w};
    uint4 o;
    o.x = (unsigned)f32_to_bf16_bits(v[0]) | ((unsigned)f32_to_bf16_bits(v[1]) << 16);
    o.y = (unsigned)f32_to_bf16_bits(v[2]) | ((unsigned)f32_to_bf16_bits(v[3]) << 16);
    o.z = (unsigned)f32_to_bf16_bits(v[4]) | ((unsigned)f32_to_bf16_bits(v[5]) << 16);
    o.w = (unsigned)f32_to_bf16_bits(v[6]) | ((unsigned)f32_to_bf16_bits(v[7]) << 16);
    ((uint4*)out)[t] = o;
}

// ---------------- weight prep: fragment-linear hi/lo bf16 ----------------
// Shared (lane,elem)->k rule for A and B packing => any k-permutation cancels:
//   elem i of lane l in k-chunk t covers k = t*32 + (l>>4)*8 + i, col = f*16 + (l&15)

__global__ __launch_bounds__(256) void prep_kernel(const float* __restrict__ W1a,
                                                   const float* __restrict__ W2a,
                                                   const float* __restrict__ Ws1,
                                                   const float* __restrict__ Ws2,
                                                   short* __restrict__ whi,
                                                   short* __restrict__ wlo) {
    int mat = blockIdx.y;  // 0..5
    const float* W;
    switch (mat) {
        case 0: W = W1a; break;
        case 1: W = W2a; break;
        case 2: W = Ws1; break;
        case 3: W = Ws2; break;
        case 4: W = Ws1 + HID * HID; break;
        default: W = Ws2 + HID * HID; break;
    }
    int tid2 = blockIdx.x * 256 + threadIdx.x;  // 0..2047
    int l = tid2 & 63;
    int ft = tid2 >> 6;       // f*4 + t
    int t = ft & 3, f = ft >> 2;
    int g = l >> 4, lm = l & 15;
    bf16x8 hv, lv;
    #pragma unroll
    for (int i = 0; i < 8; ++i) {
        int k = t * 32 + g * 8 + i;
        int n = f * 16 + lm;
        float v = W[k * HID + n];
        ushort hb = f32_to_bf16_bits(v);
        ushort lb = f32_to_bf16_bits(v - bf16bits_to_f32(hb));
        hv[i] = (short)hb;
        lv[i] = (short)lb;
    }
    size_t base = ((size_t)mat * 2048 + tid2) * 8;
    *(bf16x8*)&whi[base] = hv;
    *(bf16x8*)&wlo[base] = lv;
}

// ---------------- fused GIN layer: out = relu(mlp(x + sum_{j->i} x_j)) ----------------
// 256 thr = 4 waves per block, 16 nodes/block (grid 3125 -> ~32 waves/CU).
// Gather: wave w gathers nodes 4w..4w+3 from bf16 table (4 B/lane/row).
// GEMM: f-loop split 2 fragments per wave; LDS rows shared; 3 barriers.

__global__ __launch_bounds__(256) void fused_gin_kernel(const unsigned* __restrict__ xbf,
                                                        const int* __restrict__ csr,
                                                        const int* __restrict__ offs,
                                                        const int* __restrict__ cnt,
                                                        const short* __restrict__ w1hi,
                                                        const short* __restrict__ w1lo,
                                                        const short* __restrict__ w2hi,
                                                        const short* __restrict__ w2lo,
                                                        const float* __restrict__ b1,
                                                        const float* __restrict__ b2,
                                                        ushort* __restrict__ xoutb,
                                                        float* __restrict__ xoutf) {
    __shared__ short sHi[16][136];
    __shared__ short sLo[16][136];

    const int tid = threadIdx.x;
    const int lane = tid & 63;
    const int wid = tid >> 6;
    const int nbase = blockIdx.x * 16;     // 3125 * 16 == 50000 exactly
    const int g = lane >> 4, lm = lane & 15;

    // ---- gather phase: h[n] = x[n] + sum_j x[csr[j]] (bf16 in, f32 accum) ----
    for (int n = 0; n < 4; ++n) {
        int node = nbase + wid * 4 + n;
        int off = offs[node];
        int c = cnt[node];
        unsigned su = xbf[(size_t)node * 64 + lane];   // cols {2l, 2l+1}
        float ax = __uint_as_float(su << 16);
        float ay = __uint_as_float(su & 0xffff0000u);
        int e = 0;
        for (; e + 8 <= c; e += 8) {
            int s[8];
            #pragma unroll
            for (int q = 0; q < 8; ++q) s[q] = csr[off + e + q];
            unsigned u[8];
            #pragma unroll
            for (int q = 0; q < 8; ++q) u[q] = xbf[(size_t)s[q] * 64 + lane];
            #pragma unroll
            for (int q = 0; q < 8; ++q) {
                ax += __uint_as_float(u[q] << 16);
                ay += __uint_as_float(u[q] & 0xffff0000u);
            }
        }
        for (; e + 4 <= c; e += 4) {
            int s0 = csr[off + e], s1 = csr[off + e + 1];
            int s2 = csr[off + e + 2], s3 = csr[off + e + 3];
            unsigned u0 = xbf[(size_t)s0 * 64 + lane];
            unsigned u1 = xbf[(size_t)s1 * 64 + lane];
            unsigned u2 = xbf[(size_t)s2 * 64 + lane];
            unsigned u3 = xbf[(size_t)s3 * 64 + lane];
            ax += (__uint_as_float(u0 << 16) + __uint_as_float(u1 << 16)) +
                  (__uint_as_float(u2 << 16) + __uint_as_float(u3 << 16));
            ay += (__uint_as_float(u0 & 0xffff0000u) + __uint_as_float(u1 & 0xffff0000u)) +
                  (__uint_as_float(u2 & 0xffff0000u) + __uint_as_float(u3 & 0xffff0000u));
        }
        for (; e < c; ++e) {
            int s = csr[off + e];
            unsigned u = xbf[(size_t)s * 64 + lane];
            ax += __uint_as_float(u << 16);
            ay += __uint_as_float(u & 0xffff0000u);
        }
        // split hi/lo, pack two cols into one dword LDS write
        ushort hx = f32_to_bf16_bits(ax);
        ushort lx = f32_to_bf16_bits(ax - bf16bits_to_f32(hx));
        ushort hy = f32_to_bf16_bits(ay);
        ushort ly = f32_to_bf16_bits(ay - bf16bits_to_f32(hy));
        int row = wid * 4 + n;
        *(unsigned*)&sHi[row][2 * lane] = (unsigned)hx | ((unsigned)hy << 16);
        *(unsigned*)&sLo[row][2 * lane] = (unsigned)lx | ((unsigned)ly << 16);
    }
    __syncthreads();

    f32x4 accT[2];

    // ---- GEMM1: T = relu(h @ W1 + b1), wave computes f = {2*wid, 2*wid+1} ----
    {
        bf16x8 ahi[4], alo[4];
        #pragma unroll
        for (int t = 0; t < 4; ++t) {
            ahi[t] = *(bf16x8*)&sHi[lm][t * 32 + g * 8];
            alo[t] = *(bf16x8*)&sLo[lm][t * 32 + g * 8];
        }
        __syncthreads();   // all waves have read h before epilogue overwrites
        #pragma unroll
        for (int ff = 0; ff < 2; ++ff) {
            int f = wid * 2 + ff;
            const bf16x8* bh = (const bf16x8*)&w1hi[((size_t)(f * 4) * 64 + lane) * 8];
            const bf16x8* bl = (const bf16x8*)&w1lo[((size_t)(f * 4) * 64 + lane) * 8];
            f32x4 acc = {0.f, 0.f, 0.f, 0.f};
            #pragma unroll
            for (int t = 0; t < 4; ++t) {
                bf16x8 bhv = bh[t * 64];
                bf16x8 blv = bl[t * 64];
                acc = __builtin_amdgcn_mfma_f32_16x16x32_bf16(ahi[t], bhv, acc, 0, 0, 0);
                acc = __builtin_amdgcn_mfma_f32_16x16x32_bf16(alo[t], bhv, acc, 0, 0, 0);
                acc = __builtin_amdgcn_mfma_f32_16x16x32_bf16(ahi[t], blv, acc, 0, 0, 0);
            }
            accT[ff] = acc;
        }
    }
    // epilogue 1: bias+relu, split hi/lo, write back (C/D: row=g*4+r, col=f*16+lm)
    #pragma unroll
    for (int ff = 0; ff < 2; ++ff) {
        int f = wid * 2 + ff;
        float bv = b1[f * 16 + lm];
        #pragma unroll
        for (int r = 0; r < 4; ++r) {
            float v = accT[ff][r] + bv;
            v = v > 0.f ? v : 0.f;
            ushort hb = f32_to_bf16_bits(v);
            ushort lb = f32_to_bf16_bits(v - bf16bits_to_f32(hb));
            int m = g * 4 + r;
            sHi[m][f * 16 + lm] = (short)hb;
            sLo[m][f * 16 + lm] = (short)lb;
        }
    }
    __syncthreads();

    // ---- GEMM2: out = relu(T @ W2 + b2) ----
    {
        bf16x8 ahi[4], alo[4];
        #pragma unroll
        for (int t = 0; t < 4; ++t) {
            ahi[t] = *(bf16x8*)&sHi[lm][t * 32 + g * 8];
            alo[t] = *(bf16x8*)&sLo[lm][t * 32 + g * 8];
        }
        #pragma unroll
        for (int ff = 0; ff < 2; ++ff) {
            int f = wid * 2 + ff;
            const bf16x8* bh = (const bf16x8*)&w2hi[((size_t)(f * 4) * 64 + lane) * 8];
            const bf16x8* bl = (const bf16x8*)&w2lo[((size_t)(f * 4) * 64 + lane) * 8];
            f32x4 acc = {0.f, 0.f, 0.f, 0.f};
            #pragma unroll
            for (int t = 0; t < 4; ++t) {
                bf16x8 bhv = bh[t * 64];
                bf16x8 blv = bl[t * 64];
                acc = __builtin_amdgcn_mfma_f32_16x16x32_bf16(ahi[t], bhv, acc, 0, 0, 0);
                acc = __builtin_amdgcn_mfma_f32_16x16x32_bf16(alo[t], bhv, acc, 0, 0, 0);
                acc = __builtin_amdgcn_mfma_f32_16x16x32_bf16(ahi[t], blv, acc, 0, 0, 0);
            }
            accT[ff] = acc;
        }
    }
    // epilogue 2: bias+relu; store bf16 (next-layer gather) and/or f32 (final)
    #pragma unroll
    for (int ff = 0; ff < 2; ++ff) {
        int f = wid * 2 + ff;
        float bv = b2[f * 16 + lm];
        #pragma unroll
        for (int r = 0; r < 4; ++r) {
            float v = accT[ff][r] + bv;
            v = v > 0.f ? v : 0.f;
            int gn = nbase + g * 4 + r;
            size_t gi = (size_t)gn * HID + f * 16 + lm;
            if (xoutb) xoutb[gi] = f32_to_bf16_bits(v);
            if (xoutf) xoutf[gi] = v;
        }
    }
}

// ---------------- launch ----------------

extern "C" void kernel_launch(void* const* d_in, const int* in_sizes, int n_in,
                              void* d_out, int out_size, void* d_ws, size_t ws_size,
                              hipStream_t stream) {
    const float* feat = (const float*)d_in[0];
    const int* edge = (const int*)d_in[1];
    const int* src = edge;
    const int* dst = edge + N_EDGES;
    const float* W1a = (const float*)d_in[2];
    const float* b1a = (const float*)d_in[3];
    const float* W2a = (const float*)d_in[4];
    const float* b2a = (const float*)d_in[5];
    const float* Ws1 = (const float*)d_in[6];
    const float* bs1 = (const float*)d_in[7];
    const float* Ws2 = (const float*)d_in[8];
    const float* bs2 = (const float*)d_in[9];
    float* out = (float*)d_out;

    // ws layout: cnt | offs | cursor | gcur(pad) | csr | xbA | xbB | whi | wlo
    int* cnt = (int*)d_ws;
    int* offs = cnt + 50176;
    int* cursor = offs + 50176;
    int* gcur = cursor + 50176;
    int* csr = gcur + 64;
    ushort* xbA = (ushort*)(csr + N_EDGES);          // bf16 tables, 12.8 MB each
    ushort* xbB = xbA + (size_t)N_NODES * HID;
    short* whi = (short*)(xbB + (size_t)N_NODES * HID);
    short* wlo = whi + 6 * 2048 * 8;

    hipMemsetAsync(cnt, 0, N_NODES * sizeof(int), stream);
    hipMemsetAsync(gcur, 0, sizeof(int), stream);

    const int EB = (N_EDGES + 255) / 256;
    const int NB = (N_NODES + 255) / 256;
    conv_kernel<<<3125, 256, 0, stream>>>(feat, xbA);
    prep_kernel<<<dim3(8, 6), 256, 0, stream>>>(W1a, W2a, Ws1, Ws2, whi, wlo);
    hist_kernel<<<EB, 256, 0, stream>>>(dst, cnt);
    alloc_offsets_kernel<<<NB, 256, 0, stream>>>(cnt, offs, cursor, gcur);
    scatter_kernel<<<EB, 256, 0, stream>>>(src, dst, cursor, csr);

    const int FB = N_NODES / 16;   // 3125 blocks, 16 nodes each, exact
    const int MS = 16384;          // per-matrix fragment array size (shorts)

    // mat order: W1a, W2a, Ws1[0], Ws2[0], Ws1[1], Ws2[1]
    // buffers: A(feat) -> B -> A -> d_out
    fused_gin_kernel<<<FB, 256, 0, stream>>>((const unsigned*)xbA, csr, offs, cnt,
                                             whi + 0 * MS, wlo + 0 * MS,
                                             whi + 1 * MS, wlo + 1 * MS, b1a, b2a,
                                             xbB, nullptr);
    fused_gin_kernel<<<FB, 256, 0, stream>>>((const unsigned*)xbB, csr, offs, cnt,
                                             whi + 2 * MS, wlo + 2 * MS,
                                             whi + 3 * MS, wlo + 3 * MS, bs1, bs2,
                                             xbA, nullptr);
    fused_gin_kernel<<<FB, 256, 0, stream>>>((const unsigned*)xbA, csr, offs, cnt,
                                             whi + 4 * MS, wlo + 4 * MS,
                                             whi + 5 * MS, wlo + 5 * MS,
                                             bs1 + HID, bs2 + HID,
                                             nullptr, out);
}